// Round 16
// baseline (883.774 us; speedup 1.0000x reference)
//
#include <hip/hip_runtime.h>
#include <math.h>

#define BATCH 512
#define TT    1024
#define FF    128
#define UU    50
#define ZN    200          // 4*UU
#define NP    208          // padded N (13 * 16)
#define NTL   13           // N tiles of 16
#define MROWS (BATCH * TT) // 524288
#define BM    128          // rows per GEMM block
#define RPP   8            // rows per pass in fallback GEMM
#define ESTRIDE 212        // GEMM epilogue LDS row stride

typedef __attribute__((ext_vector_type(8))) short bhalf8;
typedef __attribute__((ext_vector_type(4))) short bhalf4;
typedef __attribute__((ext_vector_type(4))) float f32x4;

__device__ __forceinline__ float rcp_fast(float x) { return __builtin_amdgcn_rcpf(x); }
__device__ __forceinline__ float sigmoid_fast(float x) {
    return rcp_fast(1.0f + __builtin_amdgcn_exp2f(-1.442695041f * x));
}
__device__ __forceinline__ float tanh_fast(float x) {
    float e = __builtin_amdgcn_exp2f(2.885390082f * x);
    return fmaf(-2.0f, rcp_fast(e + 1.0f), 1.0f);
}
__device__ __forceinline__ unsigned short bf16_rtn(float x) {
    unsigned int u = __float_as_uint(x);
    unsigned int r = u + 0x7FFFu + ((u >> 16) & 1u);
    return (unsigned short)(r >> 16);
}
__device__ __forceinline__ float bf16_f32(unsigned short h) {
    return __uint_as_float(((unsigned int)h) << 16);
}
__device__ __forceinline__ unsigned short bf16_tr(float x) {
    return (unsigned short)(__float_as_uint(x) >> 16);
}

// ---------------- Prep: Kt_hi/Kt_lo[NP][FF] bf16 — parallel ----------------------
__global__ void prep_kt_kernel(const float* __restrict__ K,
                               unsigned short* __restrict__ kt_hi,
                               unsigned short* __restrict__ kt_lo) {
    const int idx = blockIdx.x * 256 + threadIdx.x;
    if (idx >= NP * FF) return;
    const int c = idx / FF;
    const int k = idx - c * FF;
    float v = (c < ZN) ? K[k * ZN + c] : 0.0f;
    unsigned short h = bf16_rtn(v);
    kt_hi[idx] = h;
    kt_lo[idx] = bf16_rtn(v - bf16_f32(h));
}

// ---------------- Kernel A: zx = x @ K + bias via bf16x2-split MFMA (r14) --------
__launch_bounds__(256, 2)
__global__ void xk_mfma_kernel(const float* __restrict__ x,
                               const unsigned short* __restrict__ kt_hi,
                               const unsigned short* __restrict__ kt_lo,
                               const float* __restrict__ bias,
                               float* __restrict__ zx) {
    __shared__ __align__(16) char xlds[2 * BM * FF * 2];

    const int tid = threadIdx.x;
    const size_t rowbase = (size_t)blockIdx.x * BM;
    const float* xb = x + rowbase * FF;

    const float4* gx = (const float4*)xb;
    #pragma unroll
    for (int i = 0; i < 16; ++i) {
        float4 v = gx[tid + 256 * i];
        const int fidx = (tid + 256 * i) * 4;
        const int row = fidx >> 7;
        const int col = fidx & 127;
        unsigned short h0 = bf16_tr(v.x), h1 = bf16_tr(v.y),
                       h2 = bf16_tr(v.z), h3 = bf16_tr(v.w);
        bhalf4 hv = { (short)h0, (short)h1, (short)h2, (short)h3 };
        bhalf4 lv = { (short)bf16_tr(v.x - bf16_f32(h0)),
                      (short)bf16_tr(v.y - bf16_f32(h1)),
                      (short)bf16_tr(v.z - bf16_f32(h2)),
                      (short)bf16_tr(v.w - bf16_f32(h3)) };
        const unsigned byte = (unsigned)((row << 8) + (col << 1)) ^ (((unsigned)row & 7u) << 4);
        *(bhalf4*)(xlds + byte)         = hv;
        *(bhalf4*)(xlds + 32768 + byte) = lv;
    }
    __syncthreads();

    const int w = tid >> 6, l = tid & 63;
    const int lrow = l & 15;
    const int lk   = (l >> 4) << 3;

    float bv[NTL];
    #pragma unroll
    for (int nt = 0; nt < NTL; ++nt) {
        const int cidx = nt * 16 + lrow;
        bv[nt] = (cidx < ZN) ? bias[cidx] : 0.0f;
    }

    f32x4 acc0[NTL], acc1[NTL];
    #pragma unroll
    for (int nt = 0; nt < NTL; ++nt) { acc0[nt] = (f32x4)0.0f; acc1[nt] = (f32x4)0.0f; }

    #pragma unroll
    for (int ks = 0; ks < 4; ++ks) {
        const int kbyte = (ks * 32 + lk) * 2;
        const int row0 = (w << 5) + lrow;
        const int row1 = row0 + 16;
        const unsigned b0 = (unsigned)((row0 << 8) + kbyte) ^ (((unsigned)row0 & 7u) << 4);
        const unsigned b1 = (unsigned)((row1 << 8) + kbyte) ^ (((unsigned)row1 & 7u) << 4);
        bhalf8 aH0 = *(const bhalf8*)(xlds + b0);
        bhalf8 aL0 = *(const bhalf8*)(xlds + 32768 + b0);
        bhalf8 aH1 = *(const bhalf8*)(xlds + b1);
        bhalf8 aL1 = *(const bhalf8*)(xlds + 32768 + b1);
        #pragma unroll
        for (int nt = 0; nt < NTL; ++nt) {
            const size_t koff = ((size_t)(nt * 16 + lrow) << 7) + (size_t)(ks * 32 + lk);
            bhalf8 bH = *(const bhalf8*)(kt_hi + koff);
            bhalf8 bL = *(const bhalf8*)(kt_lo + koff);
            acc0[nt] = __builtin_amdgcn_mfma_f32_16x16x32_bf16(aH0, bH, acc0[nt], 0, 0, 0);
            acc0[nt] = __builtin_amdgcn_mfma_f32_16x16x32_bf16(aH0, bL, acc0[nt], 0, 0, 0);
            acc0[nt] = __builtin_amdgcn_mfma_f32_16x16x32_bf16(aL0, bH, acc0[nt], 0, 0, 0);
            acc1[nt] = __builtin_amdgcn_mfma_f32_16x16x32_bf16(aH1, bH, acc1[nt], 0, 0, 0);
            acc1[nt] = __builtin_amdgcn_mfma_f32_16x16x32_bf16(aH1, bL, acc1[nt], 0, 0, 0);
            acc1[nt] = __builtin_amdgcn_mfma_f32_16x16x32_bf16(aL1, bH, acc1[nt], 0, 0, 0);
        }
    }

    float* elds = (float*)xlds;
    const int rsub = (l >> 4) << 2;
    #pragma unroll
    for (int half = 0; half < 2; ++half) {
        __syncthreads();
        if ((w >> 1) == half) {
            const int lr = (w & 1) * 32;
            #pragma unroll
            for (int nt = 0; nt < NTL; ++nt) {
                #pragma unroll
                for (int r = 0; r < 4; ++r) {
                    elds[(lr + rsub + r) * ESTRIDE + nt * 16 + lrow]      = acc0[nt][r] + bv[nt];
                    elds[(lr + 16 + rsub + r) * ESTRIDE + nt * 16 + lrow] = acc1[nt][r] + bv[nt];
                }
            }
        }
        __syncthreads();
        for (int f = tid; f < 64 * 50; f += 256) {
            const int row = f / 50;
            const int u = f - row * 50;
            float4 v;
            v.x = elds[row * ESTRIDE + u];
            v.y = elds[row * ESTRIDE + u + 50];
            v.z = elds[row * ESTRIDE + u + 100];
            v.w = elds[row * ESTRIDE + u + 150];
            *(float4*)&zx[(rowbase + half * 64 + row) * ZN + u * 4] = v;
        }
    }
}

// ---------------- Kernel B: scan12 — SCALAR-pinned fp32 R + LDS h-broadcast ------
// r8 proved scalar pins stay arch-resident (VGPR 248); r9's residency break came
// with the switch to f32x2 pair pins. This kernel = r8's scalar register layout +
// r9's uniform-address LDS broadcast (no readlane SGPR hazards). fp32 throughout.
// Per step: 13 ds_read_b128 (broadcast) + 200 v_fmac (4 chains) + gates; zero
// barriers (1 wave/batch, lgkm ordering).
#define ISSUE4(DST, T0) do {                                                  \
    _Pragma("unroll")                                                         \
    for (int s = 0; s < 4; ++s) {                                             \
        int tt = (T0) + s; if (tt > TT - 1) tt = TT - 1;                      \
        if (act) DST[s] = *(const float4*)&zp[(size_t)tt * ZN + l * 4];       \
    }                                                                         \
} while (0)

#define STEPS(V) do {                                                         \
    float a0 = (V).x, a1 = (V).y, a2 = (V).z, a3 = (V).w;                     \
    const float4* h4 = (const float4*)hbuf;                                   \
    _Pragma("unroll")                                                         \
    for (int q = 0; q < 12; ++q) {                                            \
        float4 hv = h4[q];                                                    \
        a0 = fmaf(hv.x, r0[4*q],   a0); a1 = fmaf(hv.x, r1[4*q],   a1);       \
        a2 = fmaf(hv.x, r2[4*q],   a2); a3 = fmaf(hv.x, r3[4*q],   a3);       \
        a0 = fmaf(hv.y, r0[4*q+1], a0); a1 = fmaf(hv.y, r1[4*q+1], a1);       \
        a2 = fmaf(hv.y, r2[4*q+1], a2); a3 = fmaf(hv.y, r3[4*q+1], a3);       \
        a0 = fmaf(hv.z, r0[4*q+2], a0); a1 = fmaf(hv.z, r1[4*q+2], a1);       \
        a2 = fmaf(hv.z, r2[4*q+2], a2); a3 = fmaf(hv.z, r3[4*q+2], a3);       \
        a0 = fmaf(hv.w, r0[4*q+3], a0); a1 = fmaf(hv.w, r1[4*q+3], a1);       \
        a2 = fmaf(hv.w, r2[4*q+3], a2); a3 = fmaf(hv.w, r3[4*q+3], a3);       \
    }                                                                         \
    {                                                                         \
        float h48 = hbuf[48], h49 = hbuf[49];                                 \
        a0 = fmaf(h48, r0[48], a0); a1 = fmaf(h48, r1[48], a1);               \
        a2 = fmaf(h48, r2[48], a2); a3 = fmaf(h48, r3[48], a3);               \
        a0 = fmaf(h49, r0[49], a0); a1 = fmaf(h49, r1[49], a1);               \
        a2 = fmaf(h49, r2[49], a2); a3 = fmaf(h49, r3[49], a3);               \
    }                                                                         \
    float gi = sigmoid_fast(a0), gf = sigmoid_fast(a1);                       \
    float gg = tanh_fast(a2),    go = sigmoid_fast(a3);                       \
    c = gf * c + gi * gg;                                                     \
    h = go * tanh_fast(c);                                                    \
    hbuf[l] = h;                          /* lanes>=50: z=0 path keeps h=0 */ \
} while (0)

#define STEPS4(SRC) do { STEPS(SRC[0]); STEPS(SRC[1]); STEPS(SRC[2]); STEPS(SRC[3]); } while (0)

__launch_bounds__(64, 1)
__global__ void lstm_scan12_kernel(const float* __restrict__ zx4,
                                   const float* __restrict__ R,
                                   const float* __restrict__ dw,
                                   const float* __restrict__ db,
                                   float* __restrict__ out) {
    const int l = threadIdx.x;           // lane; l<50 owns unit l
    const int b = blockIdx.x;            // batch
    const bool act = (l < UU);

    __shared__ __align__(16) float hbuf[64];

    // R quadrant columns in 200 SCALAR pinned VGPRs: rq[u] = R[u][l + 50q]
    float r0[UU], r1[UU], r2[UU], r3[UU];
    #pragma unroll
    for (int u = 0; u < UU; ++u) {
        r0[u] = act ? R[u * ZN + l]       : 0.0f;
        r1[u] = act ? R[u * ZN + l + 50]  : 0.0f;
        r2[u] = act ? R[u * ZN + l + 100] : 0.0f;
        r3[u] = act ? R[u * ZN + l + 150] : 0.0f;
    }
    #pragma unroll
    for (int u = 0; u < UU; ++u)
        asm volatile("" : "+v"(r0[u]), "+v"(r1[u]), "+v"(r2[u]), "+v"(r3[u]));

    const float dwv = act ? dw[l] : 0.0f;
    const float* zp = zx4 + (size_t)b * TT * ZN;

    hbuf[l] = 0.0f;                      // h(-1) = 0
    float h = 0.0f, c = 0.0f;

    float4 pf[4], qf[4];
    #pragma unroll
    for (int s = 0; s < 4; ++s) { pf[s] = (float4){0,0,0,0}; qf[s] = (float4){0,0,0,0}; }

    ISSUE4(pf, 0);
    for (int t = 0; t < TT; t += 8) {
        ISSUE4(qf, t + 4);
        STEPS4(pf);                      // steps t .. t+3
        ISSUE4(pf, t + 8);               // clamped (dead) on last iteration
        STEPS4(qf);                      // steps t+4 .. t+7
    }

    float s = act ? h * dwv : 0.0f;
    #pragma unroll
    for (int off = 32; off > 0; off >>= 1) s += __shfl_down(s, off, 64);
    if (l == 0) out[b] = s + db[0];
}

// ---------------- Fallback GEMM (permuted store) ---------------------------------
__launch_bounds__(256, 1)
__global__ void xk_gemm_kernel(const float* __restrict__ x,
                               const float* __restrict__ K,
                               const float* __restrict__ bias,
                               float* __restrict__ zx) {
    const int b = blockIdx.x;
    const int j = threadIdx.x;

    __shared__ __align__(16) float xs[2][RPP * FF];

    float kreg[FF];
    float bj = 0.0f;
    if (j < ZN) {
        #pragma unroll
        for (int k = 0; k < FF; ++k) kreg[k] = K[k * ZN + j];
        bj = bias[j];
    }
    const int jpos = (j % UU) * 4 + (j / UU);

    const float* xrow = x + (size_t)b * TT * FF;
    float* zrow = zx + (size_t)b * TT * ZN;

    ((float4*)xs[0])[threadIdx.x] = ((const float4*)xrow)[threadIdx.x];
    __syncthreads();

    const int NPASS = TT / RPP;
    for (int p = 0; p < NPASS; ++p) {
        const int cur = p & 1, nxt = cur ^ 1;
        float4 gxv;
        const bool more = (p + 1) < NPASS;
        if (more) gxv = ((const float4*)(xrow + (size_t)(p + 1) * RPP * FF))[threadIdx.x];

        if (j < ZN) {
            float acc[RPP];
            #pragma unroll
            for (int r = 0; r < RPP; ++r) acc[r] = bj;
            const float4* xb4 = (const float4*)xs[cur];
            #pragma unroll
            for (int k4 = 0; k4 < FF / 4; ++k4) {
                #pragma unroll
                for (int r = 0; r < RPP; ++r) {
                    float4 xv = xb4[r * (FF / 4) + k4];
                    acc[r] = fmaf(xv.x, kreg[4 * k4 + 0], acc[r]);
                    acc[r] = fmaf(xv.y, kreg[4 * k4 + 1], acc[r]);
                    acc[r] = fmaf(xv.z, kreg[4 * k4 + 2], acc[r]);
                    acc[r] = fmaf(xv.w, kreg[4 * k4 + 3], acc[r]);
                }
            }
            float* zpo = zrow + (size_t)p * RPP * ZN + jpos;
            #pragma unroll
            for (int r = 0; r < RPP; ++r) zpo[r * ZN] = acc[r];
        }
        if (more) ((float4*)xs[nxt])[threadIdx.x] = gxv;
        __syncthreads();
    }
}

extern "C" void kernel_launch(void* const* d_in, const int* in_sizes, int n_in,
                              void* d_out, int out_size, void* d_ws, size_t ws_size,
                              hipStream_t stream) {
    const float* x    = (const float*)d_in[0];  // [512,1024,128]
    const float* K    = (const float*)d_in[1];  // [128,200]
    const float* R    = (const float*)d_in[2];  // [50,200]
    const float* bias = (const float*)d_in[3];  // [200]
    const float* dw   = (const float*)d_in[4];  // [50,1]
    const float* db   = (const float*)d_in[5];  // [1]
    float* out = (float*)d_out;                 // [512,1]

    const size_t zx_bytes = (size_t)MROWS * ZN * sizeof(float);          // 419.43 MB
    const size_t kt_elems = (size_t)NP * FF;
    const size_t kt_bytes = kt_elems * sizeof(unsigned short);

    if (ws_size >= zx_bytes + 2 * kt_bytes) {
        float* zx = (float*)d_ws;
        unsigned short* kt_hi = (unsigned short*)((char*)d_ws + zx_bytes);
        unsigned short* kt_lo = kt_hi + kt_elems;
        prep_kt_kernel<<<(NP * FF + 255) / 256, 256, 0, stream>>>(K, kt_hi, kt_lo);
        xk_mfma_kernel<<<MROWS / BM, 256, 0, stream>>>(x, kt_hi, kt_lo, bias, zx);
        lstm_scan12_kernel<<<BATCH, 64, 0, stream>>>(zx, R, dw, db, out);
    } else if (ws_size >= zx_bytes) {
        float* zx = (float*)d_ws;
        xk_gemm_kernel<<<BATCH, 256, 0, stream>>>(x, K, bias, zx);
        lstm_scan12_kernel<<<BATCH, 64, 0, stream>>>(zx, R, dw, db, out);
    }
}

// Round 17
// 743.956 us; speedup vs baseline: 1.1879x; 1.1879x over previous
//
#include <hip/hip_runtime.h>
#include <math.h>

#define BATCH 512
#define TT    1024
#define FF    128
#define UU    50
#define ZN    200          // 4*UU
#define NP    208          // padded N (13 * 16)
#define NTL   13           // N tiles of 16
#define MROWS (BATCH * TT) // 524288
#define BM    128          // rows per GEMM block
#define RPP   8            // rows per pass in fallback GEMM
#define ESTRIDE 212        // GEMM epilogue LDS row stride

typedef __attribute__((ext_vector_type(8))) short bhalf8;
typedef __attribute__((ext_vector_type(4))) short bhalf4;
typedef __attribute__((ext_vector_type(4))) float f32x4;
typedef __attribute__((ext_vector_type(2))) float f32x2;

__device__ __forceinline__ float rcp_fast(float x) { return __builtin_amdgcn_rcpf(x); }
__device__ __forceinline__ float sigmoid_fast(float x) {
    return rcp_fast(1.0f + __builtin_amdgcn_exp2f(-1.442695041f * x));
}
__device__ __forceinline__ float tanh_fast(float x) {
    float e = __builtin_amdgcn_exp2f(2.885390082f * x);
    return fmaf(-2.0f, rcp_fast(e + 1.0f), 1.0f);
}
__device__ __forceinline__ unsigned short bf16_rtn(float x) {
    unsigned int u = __float_as_uint(x);
    unsigned int r = u + 0x7FFFu + ((u >> 16) & 1u);
    return (unsigned short)(r >> 16);
}
__device__ __forceinline__ float bf16_f32(unsigned short h) {
    return __uint_as_float(((unsigned int)h) << 16);
}
__device__ __forceinline__ unsigned short bf16_tr(float x) {
    return (unsigned short)(__float_as_uint(x) >> 16);
}
__device__ __forceinline__ void cvt8(const float4 a, const float4 b,
                                     bhalf8& hi, bhalf8& lo) {
    unsigned short h0 = bf16_tr(a.x), h1 = bf16_tr(a.y), h2 = bf16_tr(a.z), h3 = bf16_tr(a.w);
    unsigned short h4 = bf16_tr(b.x), h5 = bf16_tr(b.y), h6 = bf16_tr(b.z), h7 = bf16_tr(b.w);
    hi[0]=(short)h0; hi[1]=(short)h1; hi[2]=(short)h2; hi[3]=(short)h3;
    hi[4]=(short)h4; hi[5]=(short)h5; hi[6]=(short)h6; hi[7]=(short)h7;
    lo[0]=(short)bf16_tr(a.x - bf16_f32(h0)); lo[1]=(short)bf16_tr(a.y - bf16_f32(h1));
    lo[2]=(short)bf16_tr(a.z - bf16_f32(h2)); lo[3]=(short)bf16_tr(a.w - bf16_f32(h3));
    lo[4]=(short)bf16_tr(b.x - bf16_f32(h4)); lo[5]=(short)bf16_tr(b.y - bf16_f32(h5));
    lo[6]=(short)bf16_tr(b.z - bf16_f32(h6)); lo[7]=(short)bf16_tr(b.w - bf16_f32(h7));
}

// ---------------- Prep: Kt_hi/Kt_lo[NP][FF] bf16 — parallel ----------------------
__global__ void prep_kt_kernel(const float* __restrict__ K,
                               unsigned short* __restrict__ kt_hi,
                               unsigned short* __restrict__ kt_lo) {
    const int idx = blockIdx.x * 256 + threadIdx.x;
    if (idx >= NP * FF) return;
    const int c = idx / FF;
    const int k = idx - c * FF;
    float v = (c < ZN) ? K[k * ZN + c] : 0.0f;
    unsigned short h = bf16_rtn(v);
    kt_hi[idx] = h;
    kt_lo[idx] = bf16_rtn(v - bf16_f32(h));
}

// ---------------- Kernel A v2: direct-reg A-fragments (no LDS staging) -----------
// Wave w's A-rows are consumed only by wave w -> r14's LDS staging (stage, barrier,
// reread) was pure overhead. A-frag loaded straight to regs (pattern proven in
// r11-13 producers, absmax 1.5e-5) + r14's proven MFMA order + permute epilogue.
__launch_bounds__(256, 2)
__global__ void xk_mfma2_kernel(const float* __restrict__ x,
                                const unsigned short* __restrict__ kt_hi,
                                const unsigned short* __restrict__ kt_lo,
                                const float* __restrict__ bias,
                                float* __restrict__ zx) {
    __shared__ __align__(16) float elds[64 * ESTRIDE];   // epilogue only (54 KB)

    const int tid = threadIdx.x;
    const int w = tid >> 6, l = tid & 63;
    const int lrow = l & 15;
    const int lk   = (l >> 4) << 3;
    const size_t rowbase = (size_t)blockIdx.x * BM;

    float bv[NTL];
    #pragma unroll
    for (int nt = 0; nt < NTL; ++nt) {
        const int cidx = nt * 16 + lrow;
        bv[nt] = (cidx < ZN) ? bias[cidx] : 0.0f;
    }

    f32x4 acc0[NTL], acc1[NTL];
    #pragma unroll
    for (int nt = 0; nt < NTL; ++nt) { acc0[nt] = (f32x4)0.0f; acc1[nt] = (f32x4)0.0f; }

    // A-row base for this wave: global rows rowbase + w*32 + {lrow, lrow+16}
    const float* xr0 = x + (rowbase + (w << 5) + lrow) * FF;
    const float* xr1 = xr0 + 16 * FF;

    #pragma unroll
    for (int ks = 0; ks < 4; ++ks) {
        const int ko = ks * 32 + lk;
        float4 a0 = *(const float4*)(xr0 + ko);
        float4 a0b = *(const float4*)(xr0 + ko + 4);
        float4 a1 = *(const float4*)(xr1 + ko);
        float4 a1b = *(const float4*)(xr1 + ko + 4);
        bhalf8 aH0, aL0, aH1, aL1;
        cvt8(a0, a0b, aH0, aL0);
        cvt8(a1, a1b, aH1, aL1);
        #pragma unroll
        for (int nt = 0; nt < NTL; ++nt) {
            const size_t koff = ((size_t)(nt * 16 + lrow) << 7) + (size_t)ko;
            bhalf8 bH = *(const bhalf8*)(kt_hi + koff);
            bhalf8 bL = *(const bhalf8*)(kt_lo + koff);
            acc0[nt] = __builtin_amdgcn_mfma_f32_16x16x32_bf16(aH0, bH, acc0[nt], 0, 0, 0);
            acc0[nt] = __builtin_amdgcn_mfma_f32_16x16x32_bf16(aH0, bL, acc0[nt], 0, 0, 0);
            acc0[nt] = __builtin_amdgcn_mfma_f32_16x16x32_bf16(aL0, bH, acc0[nt], 0, 0, 0);
            acc1[nt] = __builtin_amdgcn_mfma_f32_16x16x32_bf16(aH1, bH, acc1[nt], 0, 0, 0);
            acc1[nt] = __builtin_amdgcn_mfma_f32_16x16x32_bf16(aH1, bL, acc1[nt], 0, 0, 0);
            acc1[nt] = __builtin_amdgcn_mfma_f32_16x16x32_bf16(aL1, bH, acc1[nt], 0, 0, 0);
        }
    }

    // ---- epilogue: identical to r14 (proven) — permute via LDS, coalesced zx ----
    const int rsub = (l >> 4) << 2;
    #pragma unroll
    for (int half = 0; half < 2; ++half) {
        __syncthreads();
        if ((w >> 1) == half) {
            const int lr = (w & 1) * 32;
            #pragma unroll
            for (int nt = 0; nt < NTL; ++nt) {
                #pragma unroll
                for (int r = 0; r < 4; ++r) {
                    elds[(lr + rsub + r) * ESTRIDE + nt * 16 + lrow]      = acc0[nt][r] + bv[nt];
                    elds[(lr + 16 + rsub + r) * ESTRIDE + nt * 16 + lrow] = acc1[nt][r] + bv[nt];
                }
            }
        }
        __syncthreads();
        for (int f = tid; f < 64 * 50; f += 256) {
            const int row = f / 50;
            const int u = f - row * 50;
            float4 v;
            v.x = elds[row * ESTRIDE + u];          // i
            v.y = elds[row * ESTRIDE + u + 50];     // f
            v.z = elds[row * ESTRIDE + u + 100];    // g
            v.w = elds[row * ESTRIDE + u + 150];    // o
            *(float4*)&zx[(rowbase + half * 64 + row) * ZN + u * 4] = v;
        }
    }
}

// ---------------- Kernel B: scan10 — BYTE-IDENTICAL to round-10/14 (487 us) ------
#define ISSUE4(DST, T0) do {                                                  \
    _Pragma("unroll")                                                         \
    for (int s = 0; s < 4; ++s) {                                             \
        int tt = (T0) + s; if (tt > TT - 1) tt = TT - 1;                      \
        if (act) DST[s] = *(const float4*)&zp[(size_t)tt * ZN + l * 4];       \
    }                                                                         \
} while (0)

#define STEP9(V) do {                                                         \
    f32x2 acc0 = {(V).x, 0.f}, acc1 = {(V).y, 0.f};                           \
    f32x2 acc2 = {(V).z, 0.f}, acc3 = {(V).w, 0.f};                           \
    _Pragma("unroll")                                                         \
    for (int k4 = 0; k4 < 12; ++k4) {                                         \
        float4 hv = ((const float4*)hbuf)[k4];     /* uniform addr broadcast */ \
        f32x2 hp0 = {hv.x, hv.y}, hp1 = {hv.z, hv.w};                         \
        acc0 = __builtin_elementwise_fma(hp0, rr0[2 * k4], acc0);             \
        acc1 = __builtin_elementwise_fma(hp0, rr1[2 * k4], acc1);             \
        acc2 = __builtin_elementwise_fma(hp0, rr2[2 * k4], acc2);             \
        acc3 = __builtin_elementwise_fma(hp0, rr3[2 * k4], acc3);             \
        acc0 = __builtin_elementwise_fma(hp1, rr0[2 * k4 + 1], acc0);         \
        acc1 = __builtin_elementwise_fma(hp1, rr1[2 * k4 + 1], acc1);         \
        acc2 = __builtin_elementwise_fma(hp1, rr2[2 * k4 + 1], acc2);         \
        acc3 = __builtin_elementwise_fma(hp1, rr3[2 * k4 + 1], acc3);         \
    }                                                                         \
    {                                                                         \
        f32x2 hp = ((const f32x2*)hbuf)[24];       /* h[48], h[49] */         \
        acc0 = __builtin_elementwise_fma(hp, rr0[24], acc0);                  \
        acc1 = __builtin_elementwise_fma(hp, rr1[24], acc1);                  \
        acc2 = __builtin_elementwise_fma(hp, rr2[24], acc2);                  \
        acc3 = __builtin_elementwise_fma(hp, rr3[24], acc3);                  \
    }                                                                         \
    float zi = acc0.x + acc0.y, zf = acc1.x + acc1.y;                         \
    float zg = acc2.x + acc2.y, zo = acc3.x + acc3.y;                         \
    float gi = sigmoid_fast(zi), gf = sigmoid_fast(zf);                       \
    float go = sigmoid_fast(zo), gg = tanh_fast(zg);                          \
    c = gf * c + gi * gg;                                                     \
    h = go * tanh_fast(c);                                                    \
    hbuf[l] = h;                                                              \
} while (0)

#define STEPS4(SRC) do {                                                      \
    STEP9(SRC[0]); STEP9(SRC[1]); STEP9(SRC[2]); STEP9(SRC[3]);               \
} while (0)

__launch_bounds__(64, 1)
__global__ void lstm_scan10_kernel(const float* __restrict__ zx4,
                                   const float* __restrict__ R,
                                   const float* __restrict__ dw,
                                   const float* __restrict__ db,
                                   float* __restrict__ out) {
    const int l = threadIdx.x;
    const int b = blockIdx.x;
    const bool act = (l < UU);

    __shared__ __align__(16) float hbuf[64];

    f32x2 rr0[25], rr1[25], rr2[25], rr3[25];
    #pragma unroll
    for (int p = 0; p < 25; ++p) {
        if (act) {
            rr0[p] = (f32x2){ R[(2 * p) * ZN + l],       R[(2 * p + 1) * ZN + l] };
            rr1[p] = (f32x2){ R[(2 * p) * ZN + l + 50],  R[(2 * p + 1) * ZN + l + 50] };
            rr2[p] = (f32x2){ R[(2 * p) * ZN + l + 100], R[(2 * p + 1) * ZN + l + 100] };
            rr3[p] = (f32x2){ R[(2 * p) * ZN + l + 150], R[(2 * p + 1) * ZN + l + 150] };
        } else {
            rr0[p] = (f32x2){0.f, 0.f}; rr1[p] = (f32x2){0.f, 0.f};
            rr2[p] = (f32x2){0.f, 0.f}; rr3[p] = (f32x2){0.f, 0.f};
        }
    }
    #pragma unroll
    for (int p = 0; p < 25; ++p)
        asm volatile("" : "+v"(rr0[p]), "+v"(rr1[p]), "+v"(rr2[p]), "+v"(rr3[p]));

    const float dwv = act ? dw[l] : 0.0f;
    const float* zp = zx4 + (size_t)b * TT * ZN;

    hbuf[l] = 0.0f;
    float h = 0.0f, c = 0.0f;

    float4 pf[4], qf[4];
    #pragma unroll
    for (int s = 0; s < 4; ++s) { pf[s] = (float4){0,0,0,0}; qf[s] = (float4){0,0,0,0}; }

    ISSUE4(pf, 0);
    for (int t = 0; t < TT; t += 8) {
        ISSUE4(qf, t + 4);
        STEPS4(pf);                      // steps t .. t+3
        ISSUE4(pf, t + 8);               // clamped (dead) on last iteration
        STEPS4(qf);                      // steps t+4 .. t+7
    }

    float s = act ? h * dwv : 0.0f;
    #pragma unroll
    for (int off = 32; off > 0; off >>= 1) s += __shfl_down(s, off, 64);
    if (l == 0) out[b] = s + db[0];
}

// ---------------- Fallback GEMM (permuted store) ---------------------------------
__launch_bounds__(256, 1)
__global__ void xk_gemm_kernel(const float* __restrict__ x,
                               const float* __restrict__ K,
                               const float* __restrict__ bias,
                               float* __restrict__ zx) {
    const int b = blockIdx.x;
    const int j = threadIdx.x;

    __shared__ __align__(16) float xs[2][RPP * FF];

    float kreg[FF];
    float bj = 0.0f;
    if (j < ZN) {
        #pragma unroll
        for (int k = 0; k < FF; ++k) kreg[k] = K[k * ZN + j];
        bj = bias[j];
    }
    const int jpos = (j % UU) * 4 + (j / UU);

    const float* xrow = x + (size_t)b * TT * FF;
    float* zrow = zx + (size_t)b * TT * ZN;

    ((float4*)xs[0])[threadIdx.x] = ((const float4*)xrow)[threadIdx.x];
    __syncthreads();

    const int NPASS = TT / RPP;
    for (int p = 0; p < NPASS; ++p) {
        const int cur = p & 1, nxt = cur ^ 1;
        float4 gxv;
        const bool more = (p + 1) < NPASS;
        if (more) gxv = ((const float4*)(xrow + (size_t)(p + 1) * RPP * FF))[threadIdx.x];

        if (j < ZN) {
            float acc[RPP];
            #pragma unroll
            for (int r = 0; r < RPP; ++r) acc[r] = bj;
            const float4* xb4 = (const float4*)xs[cur];
            #pragma unroll
            for (int k4 = 0; k4 < FF / 4; ++k4) {
                #pragma unroll
                for (int r = 0; r < RPP; ++r) {
                    float4 xv = xb4[r * (FF / 4) + k4];
                    acc[r] = fmaf(xv.x, kreg[4 * k4 + 0], acc[r]);
                    acc[r] = fmaf(xv.y, kreg[4 * k4 + 1], acc[r]);
                    acc[r] = fmaf(xv.z, kreg[4 * k4 + 2], acc[r]);
                    acc[r] = fmaf(xv.w, kreg[4 * k4 + 3], acc[r]);
                }
            }
            float* zpo = zrow + (size_t)p * RPP * ZN + jpos;
            #pragma unroll
            for (int r = 0; r < RPP; ++r) zpo[r * ZN] = acc[r];
        }
        if (more) ((float4*)xs[nxt])[threadIdx.x] = gxv;
        __syncthreads();
    }
}

extern "C" void kernel_launch(void* const* d_in, const int* in_sizes, int n_in,
                              void* d_out, int out_size, void* d_ws, size_t ws_size,
                              hipStream_t stream) {
    const float* x    = (const float*)d_in[0];  // [512,1024,128]
    const float* K    = (const float*)d_in[1];  // [128,200]
    const float* R    = (const float*)d_in[2];  // [50,200]
    const float* bias = (const float*)d_in[3];  // [200]
    const float* dw   = (const float*)d_in[4];  // [50,1]
    const float* db   = (const float*)d_in[5];  // [1]
    float* out = (float*)d_out;                 // [512,1]

    const size_t zx_bytes = (size_t)MROWS * ZN * sizeof(float);          // 419.43 MB
    const size_t kt_elems = (size_t)NP * FF;
    const size_t kt_bytes = kt_elems * sizeof(unsigned short);

    if (ws_size >= zx_bytes + 2 * kt_bytes) {
        float* zx = (float*)d_ws;
        unsigned short* kt_hi = (unsigned short*)((char*)d_ws + zx_bytes);
        unsigned short* kt_lo = kt_hi + kt_elems;
        prep_kt_kernel<<<(NP * FF + 255) / 256, 256, 0, stream>>>(K, kt_hi, kt_lo);
        xk_mfma2_kernel<<<MROWS / BM, 256, 0, stream>>>(x, kt_hi, kt_lo, bias, zx);
        lstm_scan10_kernel<<<BATCH, 64, 0, stream>>>(zx, R, dw, db, out);
    } else if (ws_size >= zx_bytes) {
        float* zx = (float*)d_ws;
        xk_gemm_kernel<<<BATCH, 256, 0, stream>>>(x, K, bias, zx);
        lstm_scan10_kernel<<<BATCH, 64, 0, stream>>>(zx, R, dw, db, out);
    }
}